// Round 4
// baseline (571.453 us; speedup 1.0000x reference)
//
#include <hip/hip_runtime.h>
#include <hip/hip_bf16.h>
#include <stdint.h>

#define E_ 8
#define B_ 4096
#define D_ 2048
#define T_ 2048
#define H_ 2048
#define KDIM 2048
#define NDIM 2048

typedef __attribute__((ext_vector_type(4))) float f32x4;
typedef __attribute__((ext_vector_type(4))) unsigned short u16x4;
typedef __attribute__((ext_vector_type(8))) unsigned short u16x8;
typedef __attribute__((ext_vector_type(8))) __bf16 bf16x8;

__device__ __forceinline__ unsigned short f2bf(float f) {
    __hip_bfloat16 h = __float2bfloat16(f);
    return __builtin_bit_cast(unsigned short, h);
}

__device__ __forceinline__ void gload_lds16(const void* g, void* lds) {
    __builtin_amdgcn_global_load_lds(
        (const __attribute__((address_space(1))) void*)g,
        (__attribute__((address_space(3))) void*)lds, 16, 0, 0);
}

// ---------------------------------------------------------------------------
// Gating: f32 logits (exact ranking), softmax, top-2, per-expert slot lists.
// xs is read with NON-TEMPORAL loads (read-once stream, don't thrash L3);
// all 8 row-fragments are held in registers so the A1 pack needs no re-read.
// ---------------------------------------------------------------------------
__global__ __launch_bounds__(256) void moe_gating(
    const float* __restrict__ xs, const float* __restrict__ Wg,
    const float* __restrict__ bg, float* __restrict__ out_topk,
    float* __restrict__ prob_slot, int* __restrict__ counts,
    int* __restrict__ slot_of, unsigned short* __restrict__ A1)
{
    const int b = blockIdx.x;
    const int t = threadIdx.x;
    const int wave = t >> 6, lane = t & 63;
    __shared__ float red[E_][4];
    __shared__ int sh_i0, sh_i1;

    const f32x4 wg0 = ((const f32x4*)Wg)[t];
    const f32x4 wg1 = ((const f32x4*)Wg)[t + 256];

    f32x4 xa[E_], xb[E_];
    #pragma unroll
    for (int e = 0; e < E_; ++e) {
        const f32x4* xr = (const f32x4*)(xs + ((size_t)e * B_ + b) * D_);
        xa[e] = __builtin_nontemporal_load(&xr[t]);
        xb[e] = __builtin_nontemporal_load(&xr[t + 256]);
        float p = xa[e].x*wg0.x + xa[e].y*wg0.y + xa[e].z*wg0.z + xa[e].w*wg0.w
                + xb[e].x*wg1.x + xb[e].y*wg1.y + xb[e].z*wg1.z + xb[e].w*wg1.w;
        #pragma unroll
        for (int off = 32; off >= 1; off >>= 1) p += __shfl_xor(p, off);
        if (lane == 0) red[e][wave] = p;
    }
    __syncthreads();
    if (t == 0) {
        float pr[E_];
        float mx = -3.0e38f;
        #pragma unroll
        for (int e = 0; e < E_; ++e) {
            pr[e] = red[e][0] + red[e][1] + red[e][2] + red[e][3] + bg[0];
            mx = fmaxf(mx, pr[e]);
        }
        float s = 0.f;
        #pragma unroll
        for (int e = 0; e < E_; ++e) { pr[e] = expf(pr[e] - mx); s += pr[e]; }
        float inv = 1.0f / s;
        #pragma unroll
        for (int e = 0; e < E_; ++e) pr[e] *= inv;
        int i0 = 0;
        #pragma unroll
        for (int e = 1; e < E_; ++e) if (pr[e] > pr[i0]) i0 = e;
        int i1 = (i0 == 0) ? 1 : 0;
        #pragma unroll
        for (int e = 0; e < E_; ++e) { if (e != i0 && pr[e] > pr[i1]) i1 = e; }
        float p0 = pr[i0], p1 = pr[i1];
        out_topk[2*b]    = p0;
        out_topk[2*b+1]  = p1;
        prob_slot[2*b]   = p0;
        prob_slot[2*b+1] = p1;
        int pos0 = atomicAdd(&counts[i0], 1);
        slot_of[i0 * B_ + pos0] = 2*b;
        int pos1 = atomicAdd(&counts[i1], 1);
        slot_of[i1 * B_ + pos1] = 2*b + 1;
        sh_i0 = i0; sh_i1 = i1;
    }
    __syncthreads();
    const int i0 = sh_i0, i1 = sh_i1;
    // select the two chosen rows from registers (static unroll, rule #20)
    f32x4 s0a = xa[0], s0b = xb[0], s1a = xa[0], s1b = xb[0];
    #pragma unroll
    for (int e = 0; e < E_; ++e) {
        if (i0 == e) { s0a = xa[e]; s0b = xb[e]; }
        if (i1 == e) { s1a = xa[e]; s1b = xb[e]; }
    }
    u16x4 w;
    w[0]=f2bf(s0a.x); w[1]=f2bf(s0a.y); w[2]=f2bf(s0a.z); w[3]=f2bf(s0a.w);
    ((u16x4*)(A1 + (size_t)(2*b) * D_))[t] = w;
    w[0]=f2bf(s0b.x); w[1]=f2bf(s0b.y); w[2]=f2bf(s0b.z); w[3]=f2bf(s0b.w);
    ((u16x4*)(A1 + (size_t)(2*b) * D_ + 1024))[t] = w;
    w[0]=f2bf(s1a.x); w[1]=f2bf(s1a.y); w[2]=f2bf(s1a.z); w[3]=f2bf(s1a.w);
    ((u16x4*)(A1 + (size_t)(2*b+1) * D_))[t] = w;
    w[0]=f2bf(s1b.x); w[1]=f2bf(s1b.y); w[2]=f2bf(s1b.z); w[3]=f2bf(s1b.w);
    ((u16x4*)(A1 + (size_t)(2*b+1) * D_ + 1024))[t] = w;
}

// ---------------------------------------------------------------------------
// Build compact (expert, m-tile) work list. Max Sum(ceil(n_e/256)) = 39.
// ---------------------------------------------------------------------------
__global__ void build_tiles(const int* __restrict__ counts, int* __restrict__ tiles)
{
    if (threadIdx.x == 0 && blockIdx.x == 0) {
        int n = 0;
        for (int e = 0; e < E_; ++e) {
            int te = (counts[e] + 255) >> 8;
            for (int m = 0; m < te; ++m) tiles[1 + n++] = (e << 16) | m;
        }
        tiles[0] = n;
    }
}

// ---------------------------------------------------------------------------
// Weight transpose-convert: W[e][K][N] f32 -> Wt[e][N][K] bf16, 64x64 tiles.
// W is read with NON-TEMPORAL loads (read-once stream, keep L3 for products).
// ---------------------------------------------------------------------------
__global__ __launch_bounds__(256) void wtrans(
    const float* __restrict__ W, unsigned short* __restrict__ Wt)
{
    const int e  = blockIdx.z;
    const int kb = blockIdx.x * 64;
    const int nb = blockIdx.y * 64;
    const int t  = threadIdx.x;
    __shared__ float tile[64][68];

    const float* src = W + ((size_t)e * KDIM + kb) * NDIM + nb;
    {
        const int kr = t >> 2, nc = (t & 3) * 16;
        #pragma unroll
        for (int j = 0; j < 4; ++j) {
            f32x4 v = __builtin_nontemporal_load(
                (const f32x4*)(src + (size_t)kr * NDIM + nc + j * 4));
            *(f32x4*)&tile[kr][nc + j * 4] = v;
        }
    }
    __syncthreads();
    {
        const int nn = t >> 2, kc = (t & 3) * 16;
        unsigned short wbuf[16];
        #pragma unroll
        for (int j = 0; j < 16; ++j) wbuf[j] = f2bf(tile[kc + j][nn]);
        unsigned short* dst = Wt + ((size_t)e * NDIM + nb + nn) * KDIM + kb + kc;
        *(u16x8*)dst       = *(const u16x8*)&wbuf[0];
        *((u16x8*)dst + 1) = *(const u16x8*)&wbuf[8];
    }
}

// ---------------------------------------------------------------------------
// 256x256 8-phase expert GEMM (m201-style) — UNCHANGED from round 3.
// ---------------------------------------------------------------------------
#define BAR  __builtin_amdgcn_s_barrier()
#define WLG  asm volatile("s_waitcnt lgkmcnt(0)" ::: "memory")
#define WVM4 asm volatile("s_waitcnt vmcnt(4)" ::: "memory")
#define PRIO1 __builtin_amdgcn_s_setprio(1)
#define PRIO0 __builtin_amdgcn_s_setprio(0)

#define STA(BUF,P,KT) do{ \
    gload_lds16(aptr[P][0] + (KT)*64, &As[(BUF)*2048 + 0*1024 + (P)*512 + w64]); \
    gload_lds16(aptr[P][1] + (KT)*64, &As[(BUF)*2048 + 1*1024 + (P)*512 + w64]); }while(0)
#define STB(BUF,P,KT) do{ \
    gload_lds16(bptr[P][0] + (KT)*64, &Bs[(BUF)*2048 + (0*2+seg_w)*512 + (P)*256 + w3x64]); \
    gload_lds16(bptr[P][1] + (KT)*64, &Bs[(BUF)*2048 + (1*2+seg_w)*512 + (P)*256 + w3x64]); }while(0)

#define RDA(BUF,MQ) do{ \
    _Pragma("unroll") \
    for (int mf2 = 0; mf2 < 4; ++mf2) { \
        int row = wm + ((MQ)*4 + mf2) * 16 + (lane & 15); \
        int base = (BUF)*2048 + row * 8; \
        af[mf2][0] = __builtin_bit_cast(bf16x8, As[base + ((0*4 + lg) ^ (row & 7))]); \
        af[mf2][1] = __builtin_bit_cast(bf16x8, As[base + ((1*4 + lg) ^ (row & 7))]); } }while(0)
#define RDB(BUF,NQ,DST) do{ \
    _Pragma("unroll") \
    for (int nf2 = 0; nf2 < 2; ++nf2) { \
        int row = wn + ((NQ)*2 + nf2) * 16 + (lane & 15); \
        int base = (BUF)*2048 + row * 8; \
        DST[nf2][0] = __builtin_bit_cast(bf16x8, Bs[base + ((0*4 + lg) ^ (row & 7))]); \
        DST[nf2][1] = __builtin_bit_cast(bf16x8, Bs[base + ((1*4 + lg) ^ (row & 7))]); } }while(0)
#define MM(MQ,NQ,BF) do{ \
    _Pragma("unroll") \
    for (int mf2 = 0; mf2 < 4; ++mf2) \
    _Pragma("unroll") \
    for (int nf2 = 0; nf2 < 2; ++nf2) \
    _Pragma("unroll") \
    for (int kk = 0; kk < 2; ++kk) \
        acc[(MQ)*4+mf2][(NQ)*2+nf2] = __builtin_amdgcn_mfma_f32_16x16x32_bf16( \
            af[mf2][kk], BF[nf2][kk], acc[(MQ)*4+mf2][(NQ)*2+nf2], 0, 0, 0); }while(0)

template<int LAYER>
__global__ __launch_bounds__(512, 2) void moe_gemm(
    const unsigned short* __restrict__ Abuf,
    const unsigned short* __restrict__ Wt,
    const float* __restrict__ bias,
    const int* __restrict__ counts,
    const int* __restrict__ tiles,
    const int* __restrict__ slot_of,
    const float* __restrict__ prob_slot,
    unsigned short* __restrict__ hidden_out,
    float* __restrict__ out)
{
    const int nt = tiles[0];
    if ((int)blockIdx.x >= nt) return;
    const int info = tiles[1 + blockIdx.x];
    const int e  = info >> 16;
    const int m0 = (info & 0xffff) * 256;
    const int n0 = blockIdx.y * 256;
    const int n_e = counts[e];

    const int t = threadIdx.x;
    const int lane = t & 63;
    const int w = t >> 6;
    const int wm = (w >> 2) * 128;
    const int wn = (w & 3) * 64;
    const int lg = lane >> 4;

    __shared__ u16x8 As[2 * 2048];
    __shared__ u16x8 Bs[2 * 2048];
    __shared__ int   slots_s[256];
    __shared__ float probs_s[256];

    if (t < 256) {
        int gm = m0 + t;
        int s = -1; float p = 0.f;
        if (gm < n_e) { s = slot_of[e * B_ + gm]; p = prob_slot[s]; }
        slots_s[t] = s; probs_s[t] = p;
    }
    __syncthreads();

    const int swz = ((lane & 7) ^ ((lane >> 3) & 7)) * 8;
    const int rlo = lane >> 3;
    const int seg_w = w >> 2;
    const int w3x64 = (w & 3) * 64;
    const int w64 = w * 64;

    const unsigned short* aptr[2][2];
    #pragma unroll
    for (int P = 0; P < 2; ++P)
        #pragma unroll
        for (int j = 0; j < 2; ++j) {
            int rA = j * 128 + P * 64 + w * 8 + rlo;
            int s = slots_s[rA]; if (s < 0) s = 0;
            aptr[P][j] = Abuf + (size_t)s * KDIM + swz;
        }
    const unsigned short* bptr[2][2];
    #pragma unroll
    for (int P = 0; P < 2; ++P)
        #pragma unroll
        for (int j = 0; j < 2; ++j) {
            int sseg = j * 2 + seg_w;
            int rB = sseg * 64 + P * 32 + (w & 3) * 8 + rlo;
            bptr[P][j] = Wt + ((size_t)e * NDIM + n0 + rB) * KDIM + swz;
        }

    f32x4 acc[8][4];
    #pragma unroll
    for (int i = 0; i < 8; ++i)
        #pragma unroll
        for (int j = 0; j < 4; ++j) {
            f32x4 z = {0.f, 0.f, 0.f, 0.f};
            acc[i][j] = z;
        }
    bf16x8 af[4][2], bfe[2][2], bfo[2][2];

    // prologue: buf0 <- tile0 (A-even,B-even,B-odd,A-odd), buf1 <- tile1 (A-even,B-even,B-odd)
    STA(0,0,0); STB(0,0,0); STB(0,1,0); STA(0,1,0);
    STA(1,0,1); STB(1,0,1); STB(1,1,1);
    asm volatile("s_waitcnt vmcnt(6)" ::: "memory");   // buf0 fully landed
    BAR;

    for (int i = 0; i < 16; ++i) {
        const int t1 = 2*i + 1;
        int t2 = 2*i + 2; if (t2 > 31) t2 = 31;
        int t3 = 2*i + 3; if (t3 > 31) t3 = 31;
        // p0
        RDA(0,0); RDB(0,0,bfe);
        STA(1,1,t1);
        WVM4; BAR; WLG; PRIO1; MM(0,0,bfe); PRIO0; BAR;
        // p1
        RDB(0,1,bfo);
        STA(0,0,t2);
        BAR; WLG; PRIO1; MM(0,1,bfo); PRIO0; BAR;
        // p2
        RDA(0,1);
        STB(0,0,t2);
        BAR; WLG; PRIO1; MM(1,0,bfe); PRIO0; BAR;
        // p3
        STB(0,1,t2);
        BAR; PRIO1; MM(1,1,bfo); PRIO0; BAR;
        // p4
        RDA(1,0); RDB(1,0,bfe);
        STA(0,1,t2);
        WVM4; BAR; WLG; PRIO1; MM(0,0,bfe); PRIO0; BAR;
        // p5
        RDB(1,1,bfo);
        STA(1,0,t3);
        BAR; WLG; PRIO1; MM(0,1,bfo); PRIO0; BAR;
        // p6
        RDA(1,1);
        STB(1,0,t3);
        BAR; WLG; PRIO1; MM(1,0,bfe); PRIO0; BAR;
        // p7
        STB(1,1,t3);
        BAR; PRIO1; MM(1,1,bfo); PRIO0; BAR;
    }
    asm volatile("s_waitcnt vmcnt(0)" ::: "memory");   // drain DMA before LDS dealloc

    // epilogue — C/D layout: col = lane&15, row = (lane>>4)*4 + reg
    #pragma unroll
    for (int mf = 0; mf < 8; ++mf) {
        #pragma unroll
        for (int rr = 0; rr < 4; ++rr) {
            const int rloc = wm + mf * 16 + ((lane >> 4) << 2) + rr;
            const int s = slots_s[rloc];
            if (s < 0) continue;
            #pragma unroll
            for (int nf = 0; nf < 4; ++nf) {
                const int col = n0 + wn + nf * 16 + (lane & 15);
                float v = acc[mf][nf][rr];
                if (LAYER == 1) {
                    v += bias[e * NDIM + col];
                    v = fmaxf(v, 0.f);
                    hidden_out[(size_t)s * H_ + col] = f2bf(v);
                } else {
                    v = (v + bias[e * NDIM + col]) * probs_s[rloc];
                    atomicAdd(&out[(size_t)(s >> 1) * T_ + col], v);
                }
            }
        }
    }
}

// ---------------------------------------------------------------------------
// ws layout: counts@0 (256B) | tiles@256 (256B) | slot_of | prob_slot |
//            A1[2B][D] bf16 | hidden[2B][H] bf16 | Wt[E][N][K] bf16 (shared)
// Dispatch order keeps each GEMM's inputs freshest in L3:
//   wtrans(W1) -> gating -> build -> gemm1 -> wtrans(W2) -> gemm2
// ---------------------------------------------------------------------------
extern "C" void kernel_launch(void* const* d_in, const int* in_sizes, int n_in,
                              void* d_out, int out_size, void* d_ws, size_t ws_size,
                              hipStream_t stream)
{
    const float* xs = (const float*)d_in[0];
    const float* Wg = (const float*)d_in[1];
    const float* bg = (const float*)d_in[2];
    const float* W1 = (const float*)d_in[3];
    const float* b1 = (const float*)d_in[4];
    const float* W2 = (const float*)d_in[5];
    const float* b2 = (const float*)d_in[6];

    float* out      = (float*)d_out;
    float* out_topk = out + (size_t)B_ * T_;

    char* ws = (char*)d_ws;
    int*   counts    = (int*)ws;
    int*   tiles     = (int*)(ws + 256);
    int*   slot_of   = (int*)(ws + 512);
    float* prob_slot = (float*)(ws + 512 + E_ * B_ * 4);
    size_t off = 512 + (size_t)E_ * B_ * 4 + 2 * B_ * 4;
    off = (off + 255) & ~(size_t)255;
    unsigned short* A1     = (unsigned short*)(ws + off); off += (size_t)2 * B_ * D_ * 2;
    unsigned short* hidden = (unsigned short*)(ws + off); off += (size_t)2 * B_ * H_ * 2;
    unsigned short* Wtb    = (unsigned short*)(ws + off);

    hipMemsetAsync(counts, 0, 256, stream);
    hipMemsetAsync(out, 0, (size_t)B_ * T_ * sizeof(float), stream);

    dim3 tgrid(32, 32, E_), ggrid(40, 8), blk(256), gblk(512);

    wtrans<<<tgrid, blk, 0, stream>>>(W1, Wtb);

    moe_gating<<<dim3(B_), dim3(256), 0, stream>>>(
        xs, Wg, bg, out_topk, prob_slot, counts, slot_of, A1);
    build_tiles<<<dim3(1), dim3(64), 0, stream>>>(counts, tiles);

    moe_gemm<1><<<ggrid, gblk, 0, stream>>>(
        A1, Wtb, b1, counts, tiles, slot_of, prob_slot, hidden, nullptr);

    wtrans<<<tgrid, blk, 0, stream>>>(W2, Wtb);

    moe_gemm<2><<<ggrid, gblk, 0, stream>>>(
        hidden, Wtb, b2, counts, tiles, slot_of, prob_slot, nullptr, out);
}